// Round 1
// baseline (3452.385 us; speedup 1.0000x reference)
//
#include <hip/hip_runtime.h>
#include <hip/hip_bf16.h>
#include <math.h>

#define IGNORE_INDEX (-100)
#define BETA 0.1f

// Problem constants (B=8, S=512, H=4096, V=32000)
constexpr int Mdim = 8 * 512;   // 4096 tokens
constexpr int Kdim = 4096;      // hidden
constexpr int Ndim = 32000;     // vocab
constexpr int BM = 128, BN = 128, BK = 32;
constexpr int LDA = 40;         // padded LDS stride (elems): 80B row, 16B-aligned, 2-way-max bank alias

typedef __bf16 bf16x8 __attribute__((ext_vector_type(8)));
typedef __bf16 bf16x4 __attribute__((ext_vector_type(4)));
typedef float floatx4 __attribute__((ext_vector_type(4)));

// Fused GEMM + online softmax-statistics epilogue.
// A = x (M x K, row-major, K-contig), B = weight (N x K, row-major, K-contig) -> "NT" gemm.
// Per 128x128 logits tile: accumulate per-row sum(exp(logit)) and sum(logit) via fp32 atomics,
// and scatter the target-column logit (each (row,col) exists in exactly one block -> plain store).
__global__ __launch_bounds__(256, 2)
void dpo_gemm(const float* __restrict__ x, const float* __restrict__ w,
              const int* __restrict__ target,
              float* __restrict__ sumexp, float* __restrict__ sumlog,
              float* __restrict__ tgtlogit)
{
    __shared__ __bf16 As[BM * LDA];
    __shared__ __bf16 Bs[BN * LDA];
    __shared__ int tgt_s[BM];

    const int tid  = threadIdx.x;
    const int lane = tid & 63;
    const int wid  = tid >> 6;
    const int wm   = wid & 1;       // wave row (0..1) -> 64 rows
    const int wn   = wid >> 1;      // wave col (0..1) -> 64 cols
    const int m0   = blockIdx.y * BM;
    const int n0   = blockIdx.x * BN;

    if (tid < BM) tgt_s[tid] = target[m0 + tid];

    floatx4 acc[4][4] = {};

    const int qr = lane >> 4;   // quad 0..3
    const int cr = lane & 15;

    for (int k0 = 0; k0 < Kdim; k0 += BK) {
        __syncthreads();   // previous iter's fragment reads complete before overwrite
        // Stage A tile: 128 rows x 32 k (fp32 -> bf16). 1024 float4 / 256 thr = 4 each.
        #pragma unroll
        for (int i = 0; i < 4; ++i) {
            int idx = tid + i * 256;
            int row = idx >> 3;
            int c4  = (idx & 7) * 4;
            float4 v = *(const float4*)(x + (size_t)(m0 + row) * Kdim + k0 + c4);
            bf16x4 p;
            p[0] = (__bf16)v.x; p[1] = (__bf16)v.y; p[2] = (__bf16)v.z; p[3] = (__bf16)v.w;
            *(bf16x4*)&As[row * LDA + c4] = p;
        }
        // Stage B tile (weight rows = vocab cols of this block)
        #pragma unroll
        for (int i = 0; i < 4; ++i) {
            int idx = tid + i * 256;
            int row = idx >> 3;
            int c4  = (idx & 7) * 4;
            float4 v = *(const float4*)(w + (size_t)(n0 + row) * Kdim + k0 + c4);
            bf16x4 p;
            p[0] = (__bf16)v.x; p[1] = (__bf16)v.y; p[2] = (__bf16)v.z; p[3] = (__bf16)v.w;
            *(bf16x4*)&Bs[row * LDA + c4] = p;
        }
        __syncthreads();

        // Fragment loads: A[m=lane&15][k=quad*8+j]; B[k=quad*8+j][n=lane&15] (from K-major tiles)
        bf16x8 afrag[4], bfrag[4];
        #pragma unroll
        for (int mi = 0; mi < 4; ++mi)
            afrag[mi] = *(const bf16x8*)&As[(wm * 64 + mi * 16 + cr) * LDA + qr * 8];
        #pragma unroll
        for (int ni = 0; ni < 4; ++ni)
            bfrag[ni] = *(const bf16x8*)&Bs[(wn * 64 + ni * 16 + cr) * LDA + qr * 8];

        #pragma unroll
        for (int mi = 0; mi < 4; ++mi)
            #pragma unroll
            for (int ni = 0; ni < 4; ++ni)
                acc[mi][ni] = __builtin_amdgcn_mfma_f32_16x16x32_bf16(
                    afrag[mi], bfrag[ni], acc[mi][ni], 0, 0, 0);
    }

    // Epilogue: C/D layout col=lane&15, row=(lane>>4)*4+reg [m89-verified].
    #pragma unroll
    for (int mi = 0; mi < 4; ++mi) {
        #pragma unroll
        for (int reg = 0; reg < 4; ++reg) {
            const int lrow = wm * 64 + mi * 16 + qr * 4 + reg;
            const int grow = m0 + lrow;
            const int t = tgt_s[lrow];
            float se = 0.f, sl = 0.f;
            #pragma unroll
            for (int ni = 0; ni < 4; ++ni) {
                float v = acc[mi][ni][reg];
                int gcol = n0 + wn * 64 + ni * 16 + cr;
                if (t == gcol) tgtlogit[grow] = v;   // unique owner globally
                se += __expf(v);
                sl += v;
            }
            // reduce across the 16 lanes sharing this row (xor within lane&15)
            #pragma unroll
            for (int s = 1; s < 16; s <<= 1) {
                se += __shfl_xor(se, s, 64);
                sl += __shfl_xor(sl, s, 64);
            }
            if (cr == 0) {
                atomicAdd(&sumexp[grow], se);
                atomicAdd(&sumlog[grow], sl);
            }
        }
    }
}

// One block, 8 waves: wave w reduces sequence w (512 tokens).
__global__ void dpo_finalize(const float* __restrict__ sumexp,
                             const float* __restrict__ sumlog,
                             const float* __restrict__ tgtlogit,
                             const int* __restrict__ target,
                             float* __restrict__ out)
{
    __shared__ float s_logp[8], s_sl[8];
    const int lane = threadIdx.x & 63;
    const int w    = threadIdx.x >> 6;   // sequence index 0..7

    float lp = 0.f, cnt = 0.f, sl = 0.f;
    #pragma unroll
    for (int i = 0; i < 8; ++i) {
        int t  = w * 512 + i * 64 + lane;
        int tg = target[t];
        if (tg != IGNORE_INDEX) {
            lp  += tgtlogit[t] - logf(sumexp[t]);
            cnt += 1.f;
        }
        sl += sumlog[t];
    }
    #pragma unroll
    for (int s = 1; s < 64; s <<= 1) {
        lp  += __shfl_xor(lp, s, 64);
        cnt += __shfl_xor(cnt, s, 64);
        sl  += __shfl_xor(sl, s, 64);
    }
    if (lane == 0) { s_logp[w] = lp / cnt; s_sl[w] = sl; }
    __syncthreads();

    if (threadIdx.x == 0) {
        float cm = 0.f, rm = 0.f, loss = 0.f;
        for (int i = 0; i < 4; ++i) { cm += s_sl[i]; rm += s_sl[4 + i]; }
        const float denom = 4.f * 512.f * 32000.f;
        cm /= denom; rm /= denom;
        for (int i = 0; i < 4; ++i) {
            float d = BETA * (s_logp[i] - s_logp[4 + i]);
            // -log_sigmoid(d) = log(1+exp(-d)), numerically stable both signs
            float l = (d > 0.f) ? log1pf(expf(-d)) : (-d + log1pf(expf(d)));
            loss += l;
        }
        loss *= 0.25f;
        out[0] = loss;
        for (int i = 0; i < 4; ++i) out[1 + i] = s_logp[i];
        for (int i = 0; i < 4; ++i) out[5 + i] = s_logp[4 + i];
        out[9]  = cm;
        out[10] = rm;
        out[11] = 0.f;   // nll_loss
    }
}

extern "C" void kernel_launch(void* const* d_in, const int* in_sizes, int n_in,
                              void* d_out, int out_size, void* d_ws, size_t ws_size,
                              hipStream_t stream) {
    const float* x      = (const float*)d_in[0];   // (8,512,4096) fp32
    const float* wgt    = (const float*)d_in[1];   // (32000,4096) fp32
    const int*   target = (const int*)d_in[2];     // (8,512) int32
    float* out = (float*)d_out;

    float* sumexp   = (float*)d_ws;            // [4096]
    float* sumlog   = sumexp + Mdim;           // [4096]
    float* tgtlogit = sumlog + Mdim;           // [4096] (masked tokens never written; masked in finalize)

    // zero the atomic accumulators (ws is re-poisoned to 0xAA before every call)
    hipMemsetAsync(d_ws, 0, 2 * Mdim * sizeof(float), stream);

    dim3 grid(Ndim / BN, Mdim / BM);   // (250, 32)
    dpo_gemm<<<grid, 256, 0, stream>>>(x, wgt, target, sumexp, sumlog, tgtlogit);
    dpo_finalize<<<1, 512, 0, stream>>>(sumexp, sumlog, tgtlogit, target, out);
}

// Round 2
// 1996.352 us; speedup vs baseline: 1.7293x; 1.7293x over previous
//
#include <hip/hip_runtime.h>
#include <hip/hip_bf16.h>
#include <math.h>

#define IGNORE_INDEX (-100)
#define BETA 0.1f

// Problem constants (B=8, S=512, H=4096, V=32000)
constexpr int Mdim = 8 * 512;   // 4096 tokens
constexpr int Kdim = 4096;      // hidden
constexpr int Ndim = 32000;     // vocab
constexpr int BM = 128, BN = 128, BK = 32;
constexpr int MT = Mdim / BM;   // 32 m-tiles
constexpr int NT = Ndim / BN;   // 250 n-tiles

typedef __bf16 bf16x8 __attribute__((ext_vector_type(8)));
typedef __bf16 bf16x4 __attribute__((ext_vector_type(4)));
typedef float floatx4 __attribute__((ext_vector_type(4)));

#define GPTR(p) ((const __attribute__((address_space(1))) void*)(p))
#define LPTR(p) ((__attribute__((address_space(3))) void*)(p))

// fp32 -> bf16 pre-convert (8 elems/thread, n % 8 == 0)
__global__ void cvt_f32_bf16(const float* __restrict__ src, __bf16* __restrict__ dst, long n) {
    long i = ((long)blockIdx.x * blockDim.x + threadIdx.x) * 8;
    if (i >= n) return;
    float4 a = *(const float4*)(src + i);
    float4 b = *(const float4*)(src + i + 4);
    bf16x8 p;
    p[0] = (__bf16)a.x; p[1] = (__bf16)a.y; p[2] = (__bf16)a.z; p[3] = (__bf16)a.w;
    p[4] = (__bf16)b.x; p[5] = (__bf16)b.y; p[6] = (__bf16)b.z; p[7] = (__bf16)b.w;
    *(bf16x8*)(dst + i) = p;
}

// m97-structure GEMM (global_load_lds width=16, unpadded LDS) + fused softmax-stat epilogue.
// A = x_bf16 (M x K, K-contig), B = w_bf16 (N x K, K-contig). 1D grid, m-tile fastest for
// LLC locality on the weight (resident blocks span all 32 m-tiles).
__global__ __launch_bounds__(256, 2)
void dpo_gemm_bf16(const __bf16* __restrict__ x, const __bf16* __restrict__ w,
                   const int* __restrict__ target,
                   float* __restrict__ sumexp, float* __restrict__ sumlog,
                   float* __restrict__ tgtlogit)
{
    __shared__ __bf16 As[BM * BK];   // 8 KB, row-major [128][32], NO padding (global_load_lds)
    __shared__ __bf16 Bs[BN * BK];   // 8 KB
    __shared__ int tgt_s[BM];

    const int tid  = threadIdx.x;
    const int lane = tid & 63;
    const int wid  = tid >> 6;
    const int wm   = wid & 1;        // wave row (0..1) -> 64 rows
    const int wn   = wid >> 1;       // wave col (0..1) -> 64 cols
    const int bid  = blockIdx.x;
    const int m0   = (bid & (MT - 1)) * BM;   // m-tile fastest
    const int n0   = (bid / MT) * BN;

    if (tid < BM) tgt_s[tid] = target[m0 + tid];

    floatx4 acc[4][4] = {};

    const int qr = lane >> 4;   // quad 0..3
    const int cr = lane & 15;

    // staging geometry: wave wid, issue i in {0,1}: lane l -> row = wid*32 + i*16 + l/4,
    // k-chunk = (l&3)*8. LDS dst = tile + wid*1024 + i*512 elems (lane*16B implicit).
    const int srow = wid * 32 + (lane >> 2);
    const int kc8  = (lane & 3) * 8;
    const __bf16* xg = x + (size_t)(m0 + srow) * Kdim + kc8;
    const __bf16* wg = w + (size_t)(n0 + srow) * Kdim + kc8;
    __bf16* As_w = As + wid * 1024;   // elems; issue 1 at +512
    __bf16* Bs_w = Bs + wid * 1024;

    for (int k0 = 0; k0 < Kdim; k0 += BK) {
        __syncthreads();   // previous iter's fragment reads complete before overwrite
        __builtin_amdgcn_global_load_lds(GPTR(xg + k0),              LPTR(As_w),       16, 0, 0);
        __builtin_amdgcn_global_load_lds(GPTR(xg + k0 + 16 * Kdim),  LPTR(As_w + 512), 16, 0, 0);
        __builtin_amdgcn_global_load_lds(GPTR(wg + k0),              LPTR(Bs_w),       16, 0, 0);
        __builtin_amdgcn_global_load_lds(GPTR(wg + k0 + 16 * Kdim),  LPTR(Bs_w + 512), 16, 0, 0);
        __syncthreads();

        bf16x8 afrag[4], bfrag[4];
        #pragma unroll
        for (int mi = 0; mi < 4; ++mi)
            afrag[mi] = *(const bf16x8*)&As[(wm * 64 + mi * 16 + cr) * BK + qr * 8];
        #pragma unroll
        for (int ni = 0; ni < 4; ++ni)
            bfrag[ni] = *(const bf16x8*)&Bs[(wn * 64 + ni * 16 + cr) * BK + qr * 8];

        #pragma unroll
        for (int mi = 0; mi < 4; ++mi)
            #pragma unroll
            for (int ni = 0; ni < 4; ++ni)
                acc[mi][ni] = __builtin_amdgcn_mfma_f32_16x16x32_bf16(
                    afrag[mi], bfrag[ni], acc[mi][ni], 0, 0, 0);
    }

    // Epilogue: C/D layout col=lane&15, row=(lane>>4)*4+reg [m89-verified].
    #pragma unroll
    for (int mi = 0; mi < 4; ++mi) {
        #pragma unroll
        for (int reg = 0; reg < 4; ++reg) {
            const int lrow = wm * 64 + mi * 16 + qr * 4 + reg;
            const int grow = m0 + lrow;
            const int t = tgt_s[lrow];
            float se = 0.f, sl = 0.f;
            #pragma unroll
            for (int ni = 0; ni < 4; ++ni) {
                float v = acc[mi][ni][reg];
                int gcol = n0 + wn * 64 + ni * 16 + cr;
                if (t == gcol) tgtlogit[grow] = v;   // unique owner globally
                se += __expf(v);
                sl += v;
            }
            #pragma unroll
            for (int s = 1; s < 16; s <<= 1) {
                se += __shfl_xor(se, s, 64);
                sl += __shfl_xor(sl, s, 64);
            }
            if (cr == 0) {
                atomicAdd(&sumexp[grow], se);
                atomicAdd(&sumlog[grow], sl);
            }
        }
    }
}

// Fallback (ws too small): fp32-staged GEMM with the same swizzled 1D grid.
__global__ __launch_bounds__(256, 2)
void dpo_gemm_f32(const float* __restrict__ x, const float* __restrict__ w,
                  const int* __restrict__ target,
                  float* __restrict__ sumexp, float* __restrict__ sumlog,
                  float* __restrict__ tgtlogit)
{
    constexpr int LDA = 40;
    __shared__ __bf16 As[BM * LDA];
    __shared__ __bf16 Bs[BN * LDA];
    __shared__ int tgt_s[BM];

    const int tid  = threadIdx.x;
    const int lane = tid & 63;
    const int wid  = tid >> 6;
    const int wm   = wid & 1;
    const int wn   = wid >> 1;
    const int bid  = blockIdx.x;
    const int m0   = (bid & (MT - 1)) * BM;
    const int n0   = (bid / MT) * BN;

    if (tid < BM) tgt_s[tid] = target[m0 + tid];

    floatx4 acc[4][4] = {};
    const int qr = lane >> 4;
    const int cr = lane & 15;

    for (int k0 = 0; k0 < Kdim; k0 += BK) {
        __syncthreads();
        #pragma unroll
        for (int i = 0; i < 4; ++i) {
            int idx = tid + i * 256;
            int row = idx >> 3;
            int c4  = (idx & 7) * 4;
            float4 v = *(const float4*)(x + (size_t)(m0 + row) * Kdim + k0 + c4);
            bf16x4 p;
            p[0] = (__bf16)v.x; p[1] = (__bf16)v.y; p[2] = (__bf16)v.z; p[3] = (__bf16)v.w;
            *(bf16x4*)&As[row * LDA + c4] = p;
        }
        #pragma unroll
        for (int i = 0; i < 4; ++i) {
            int idx = tid + i * 256;
            int row = idx >> 3;
            int c4  = (idx & 7) * 4;
            float4 v = *(const float4*)(w + (size_t)(n0 + row) * Kdim + k0 + c4);
            bf16x4 p;
            p[0] = (__bf16)v.x; p[1] = (__bf16)v.y; p[2] = (__bf16)v.z; p[3] = (__bf16)v.w;
            *(bf16x4*)&Bs[row * LDA + c4] = p;
        }
        __syncthreads();

        bf16x8 afrag[4], bfrag[4];
        #pragma unroll
        for (int mi = 0; mi < 4; ++mi)
            afrag[mi] = *(const bf16x8*)&As[(wm * 64 + mi * 16 + cr) * LDA + qr * 8];
        #pragma unroll
        for (int ni = 0; ni < 4; ++ni)
            bfrag[ni] = *(const bf16x8*)&Bs[(wn * 64 + ni * 16 + cr) * LDA + qr * 8];

        #pragma unroll
        for (int mi = 0; mi < 4; ++mi)
            #pragma unroll
            for (int ni = 0; ni < 4; ++ni)
                acc[mi][ni] = __builtin_amdgcn_mfma_f32_16x16x32_bf16(
                    afrag[mi], bfrag[ni], acc[mi][ni], 0, 0, 0);
    }

    #pragma unroll
    for (int mi = 0; mi < 4; ++mi) {
        #pragma unroll
        for (int reg = 0; reg < 4; ++reg) {
            const int lrow = wm * 64 + mi * 16 + qr * 4 + reg;
            const int grow = m0 + lrow;
            const int t = tgt_s[lrow];
            float se = 0.f, sl = 0.f;
            #pragma unroll
            for (int ni = 0; ni < 4; ++ni) {
                float v = acc[mi][ni][reg];
                int gcol = n0 + wn * 64 + ni * 16 + cr;
                if (t == gcol) tgtlogit[grow] = v;
                se += __expf(v);
                sl += v;
            }
            #pragma unroll
            for (int s = 1; s < 16; s <<= 1) {
                se += __shfl_xor(se, s, 64);
                sl += __shfl_xor(sl, s, 64);
            }
            if (cr == 0) {
                atomicAdd(&sumexp[grow], se);
                atomicAdd(&sumlog[grow], sl);
            }
        }
    }
}

// One block, 8 waves: wave w reduces sequence w (512 tokens).
__global__ void dpo_finalize(const float* __restrict__ sumexp,
                             const float* __restrict__ sumlog,
                             const float* __restrict__ tgtlogit,
                             const int* __restrict__ target,
                             float* __restrict__ out)
{
    __shared__ float s_logp[8], s_sl[8];
    const int lane = threadIdx.x & 63;
    const int w    = threadIdx.x >> 6;

    float lp = 0.f, cnt = 0.f, sl = 0.f;
    #pragma unroll
    for (int i = 0; i < 8; ++i) {
        int t  = w * 512 + i * 64 + lane;
        int tg = target[t];
        if (tg != IGNORE_INDEX) {
            lp  += tgtlogit[t] - logf(sumexp[t]);
            cnt += 1.f;
        }
        sl += sumlog[t];
    }
    #pragma unroll
    for (int s = 1; s < 64; s <<= 1) {
        lp  += __shfl_xor(lp, s, 64);
        cnt += __shfl_xor(cnt, s, 64);
        sl  += __shfl_xor(sl, s, 64);
    }
    if (lane == 0) { s_logp[w] = lp / cnt; s_sl[w] = sl; }
    __syncthreads();

    if (threadIdx.x == 0) {
        float cm = 0.f, rm = 0.f, loss = 0.f;
        for (int i = 0; i < 4; ++i) { cm += s_sl[i]; rm += s_sl[4 + i]; }
        const float denom = 4.f * 512.f * 32000.f;
        cm /= denom; rm /= denom;
        for (int i = 0; i < 4; ++i) {
            float d = BETA * (s_logp[i] - s_logp[4 + i]);
            float l = (d > 0.f) ? log1pf(expf(-d)) : (-d + log1pf(expf(d)));
            loss += l;
        }
        loss *= 0.25f;
        out[0] = loss;
        for (int i = 0; i < 4; ++i) out[1 + i] = s_logp[i];
        for (int i = 0; i < 4; ++i) out[5 + i] = s_logp[4 + i];
        out[9]  = cm;
        out[10] = rm;
        out[11] = 0.f;
    }
}

extern "C" void kernel_launch(void* const* d_in, const int* in_sizes, int n_in,
                              void* d_out, int out_size, void* d_ws, size_t ws_size,
                              hipStream_t stream) {
    const float* x      = (const float*)d_in[0];   // (8,512,4096) fp32
    const float* wgt    = (const float*)d_in[1];   // (32000,4096) fp32
    const int*   target = (const int*)d_in[2];     // (8,512) int32
    float* out = (float*)d_out;

    // ws layout: [sumexp 4096][sumlog 4096][tgtlogit 4096] floats, then bf16 x, then bf16 w
    float* sumexp   = (float*)d_ws;
    float* sumlog   = sumexp + Mdim;
    float* tgtlogit = sumlog + Mdim;
    char*  base     = (char*)d_ws + 3 * Mdim * sizeof(float);          // 49152 B
    __bf16* xbf     = (__bf16*)base;                                   // 33,554,432 B
    __bf16* wbf     = (__bf16*)(base + (size_t)Mdim * Kdim * 2);       // 262,144,000 B

    const size_t ws_needed = 3 * Mdim * sizeof(float)
                           + (size_t)Mdim * Kdim * 2
                           + (size_t)Ndim * Kdim * 2;

    hipMemsetAsync(d_ws, 0, 2 * Mdim * sizeof(float), stream);   // zero atomic accumulators

    if (ws_size >= ws_needed) {
        const long nx = (long)Mdim * Kdim;       // 16,777,216
        const long nw = (long)Ndim * Kdim;       // 131,072,000
        cvt_f32_bf16<<<(int)(nx / 8 / 256), 256, 0, stream>>>(x,   xbf, nx);
        cvt_f32_bf16<<<(int)(nw / 8 / 256), 256, 0, stream>>>(wgt, wbf, nw);
        dpo_gemm_bf16<<<MT * NT, 256, 0, stream>>>(xbf, wbf, target, sumexp, sumlog, tgtlogit);
    } else {
        dpo_gemm_f32<<<MT * NT, 256, 0, stream>>>(x, wgt, target, sumexp, sumlog, tgtlogit);
    }
    dpo_finalize<<<1, 512, 0, stream>>>(sumexp, sumlog, tgtlogit, target, out);
}

// Round 3
// 1407.643 us; speedup vs baseline: 2.4526x; 1.4182x over previous
//
#include <hip/hip_runtime.h>
#include <hip/hip_bf16.h>
#include <math.h>

#define IGNORE_INDEX (-100)
#define BETA 0.1f

// Problem constants (B=8, S=512, H=4096, V=32000)
constexpr int Mdim = 8 * 512;   // 4096 tokens
constexpr int Kdim = 4096;      // hidden
constexpr int Ndim = 32000;     // vocab
constexpr int BM = 128, BN = 128;
constexpr int BK8 = 128;        // K per stage in fp8 path (one mfma-K)
constexpr int MT = Mdim / BM;   // 32 m-tiles
constexpr int NT = Ndim / BN;   // 250 n-tiles

typedef __bf16 bf16x8 __attribute__((ext_vector_type(8)));
typedef __bf16 bf16x4 __attribute__((ext_vector_type(4)));
typedef float  floatx4 __attribute__((ext_vector_type(4)));
typedef int    v8i __attribute__((ext_vector_type(8)));
typedef int    v4i __attribute__((ext_vector_type(4)));

#define GPTR(p) ((const __attribute__((address_space(1))) void*)(p))
#define LPTR(p) ((__attribute__((address_space(3))) void*)(p))

// fp32 -> fp8 e4m3 via HW v_cvt_pk_fp8_f32. 16 elems/thread.
__global__ void cvt_f32_fp8(const float* __restrict__ src, uint* __restrict__ dst, long n) {
    long t = (long)blockIdx.x * blockDim.x + threadIdx.x;
    if (t * 16 >= n) return;
    const float4* s = (const float4*)(src + t * 16);
    float4 a = s[0], b = s[1], c = s[2], d = s[3];
    int r0 = __builtin_amdgcn_cvt_pk_fp8_f32(a.x, a.y, 0, false);
    r0     = __builtin_amdgcn_cvt_pk_fp8_f32(a.z, a.w, r0, true);
    int r1 = __builtin_amdgcn_cvt_pk_fp8_f32(b.x, b.y, 0, false);
    r1     = __builtin_amdgcn_cvt_pk_fp8_f32(b.z, b.w, r1, true);
    int r2 = __builtin_amdgcn_cvt_pk_fp8_f32(c.x, c.y, 0, false);
    r2     = __builtin_amdgcn_cvt_pk_fp8_f32(c.z, c.w, r2, true);
    int r3 = __builtin_amdgcn_cvt_pk_fp8_f32(d.x, d.y, 0, false);
    r3     = __builtin_amdgcn_cvt_pk_fp8_f32(d.z, d.w, r3, true);
    uint4 o; o.x = r0; o.y = r1; o.z = r2; o.w = r3;
    *(uint4*)(dst + t * 4) = o;
}

// MX-fp8 GEMM (unit E8M0 scales = plain fp8 matmul at the 4.6 PF MX rate) + fused
// softmax-stat epilogue. A = x8 (M x K fp8, K-contig), B = w8 (N x K fp8).
// LDS layout XOR-swizzled: LDS[row][c] = G[row][c ^ (row&7)] (16B chunks), applied on the
// GLOBAL side so global_load_lds's (base + lane*16) scatter stays legal. Fragment reads
// then spread uniformly over all 8 chunk groups -> conflict-optimal.
__global__ __launch_bounds__(256, 2)
void dpo_gemm_fp8(const unsigned char* __restrict__ x8, const unsigned char* __restrict__ w8,
                  const int* __restrict__ target,
                  float* __restrict__ sumexp, float* __restrict__ sumlog,
                  float* __restrict__ tgtlogit)
{
    __shared__ unsigned char As[BM * BK8];   // 16 KB
    __shared__ unsigned char Bs[BN * BK8];   // 16 KB
    __shared__ int tgt_s[BM];

    const int tid  = threadIdx.x;
    const int lane = tid & 63;
    const int wid  = tid >> 6;
    const int wm   = wid & 1;        // wave row (0..1) -> 64 rows
    const int wn   = wid >> 1;       // wave col (0..1) -> 64 cols
    const int bid  = blockIdx.x;
    const int m0   = (bid & (MT - 1)) * BM;   // m-tile fastest (weight LLC reuse)
    const int n0   = (bid / MT) * BN;

    if (tid < BM) tgt_s[tid] = target[m0 + tid];

    floatx4 acc[4][4] = {};

    const int qr = lane >> 4;   // quad 0..3
    const int cr = lane & 15;

    // staging geometry: wave wid, issue i in {0..3}: lane l -> row = i*32 + wid*8 + (l>>3),
    // global 16B chunk = (l&7) ^ (l>>3)  [row&7 == l>>3 since i*32+wid*8 is mult of 8].
    const int srow   = lane >> 3;               // 0..7
    const int schunk = (lane & 7) ^ srow;       // swizzled chunk
    const unsigned char* xg = x8 + (size_t)(m0 + wid * 8 + srow) * Kdim + schunk * 16;
    const unsigned char* wg = w8 + (size_t)(n0 + wid * 8 + srow) * Kdim + schunk * 16;
    unsigned char* As_w = As + wid * 1024;   // bytes; issue i at +i*4096
    unsigned char* Bs_w = Bs + wid * 1024;

    for (int k0 = 0; k0 < Kdim; k0 += BK8) {
        __syncthreads();   // previous iter's fragment reads complete before overwrite
        #pragma unroll
        for (int i = 0; i < 4; ++i) {
            __builtin_amdgcn_global_load_lds(GPTR(xg + k0 + (size_t)i * 32 * Kdim),
                                             LPTR(As_w + i * 4096), 16, 0, 0);
            __builtin_amdgcn_global_load_lds(GPTR(wg + k0 + (size_t)i * 32 * Kdim),
                                             LPTR(Bs_w + i * 4096), 16, 0, 0);
        }
        __syncthreads();

        // Fragments: A[m=lane&15][k=quad*32+j], j=0..31 (8 dwords). Global k-chunks 2q,2q+1
        // live at LDS chunks (2q)^s, (2q+1)^s with s = row&7 = cr&7.
        const int s  = cr & 7;
        const int c0 = (2 * qr) ^ s;       // LDS chunk holding k [q*32 .. q*32+15]
        const int c1 = (2 * qr + 1) ^ s;   // LDS chunk holding k [q*32+16 .. q*32+31]

        v8i afrag[4], bfrag[4];
        #pragma unroll
        for (int mi = 0; mi < 4; ++mi) {
            const int base = (wm * 64 + mi * 16 + cr) * BK8;
            v4i lo = *(const v4i*)&As[base + c0 * 16];
            v4i hi = *(const v4i*)&As[base + c1 * 16];
            afrag[mi] = __builtin_shufflevector(lo, hi, 0, 1, 2, 3, 4, 5, 6, 7);
        }
        #pragma unroll
        for (int ni = 0; ni < 4; ++ni) {
            const int base = (wn * 64 + ni * 16 + cr) * BK8;
            v4i lo = *(const v4i*)&Bs[base + c0 * 16];
            v4i hi = *(const v4i*)&Bs[base + c1 * 16];
            bfrag[ni] = __builtin_shufflevector(lo, hi, 0, 1, 2, 3, 4, 5, 6, 7);
        }

        #pragma unroll
        for (int mi = 0; mi < 4; ++mi)
            #pragma unroll
            for (int ni = 0; ni < 4; ++ni)
                acc[mi][ni] = __builtin_amdgcn_mfma_scale_f32_16x16x128_f8f6f4(
                    afrag[mi], bfrag[ni], acc[mi][ni],
                    0 /*cbsz: A=fp8 e4m3*/, 0 /*blgp: B=fp8 e4m3*/,
                    0, 0x7F7F7F7F,   // scale_a opsel, unit scales (E8M0 127 = 1.0)
                    0, 0x7F7F7F7F);  // scale_b
    }

    // Epilogue: C/D layout col=lane&15, row=(lane>>4)*4+reg (shape-determined, m121-128).
    #pragma unroll
    for (int mi = 0; mi < 4; ++mi) {
        #pragma unroll
        for (int reg = 0; reg < 4; ++reg) {
            const int lrow = wm * 64 + mi * 16 + qr * 4 + reg;
            const int grow = m0 + lrow;
            const int t = tgt_s[lrow];
            float se = 0.f, sl = 0.f;
            #pragma unroll
            for (int ni = 0; ni < 4; ++ni) {
                float v = acc[mi][ni][reg];
                int gcol = n0 + wn * 64 + ni * 16 + cr;
                if (t == gcol) tgtlogit[grow] = v;   // unique owner globally
                se += __expf(v);
                sl += v;
            }
            #pragma unroll
            for (int st = 1; st < 16; st <<= 1) {
                se += __shfl_xor(se, st, 64);
                sl += __shfl_xor(sl, st, 64);
            }
            if (cr == 0) {
                atomicAdd(&sumexp[grow], se);
                atomicAdd(&sumlog[grow], sl);
            }
        }
    }
}

// Fallback (ws too small): fp32-staged bf16 GEMM with the same swizzled 1D grid.
__global__ __launch_bounds__(256, 2)
void dpo_gemm_f32(const float* __restrict__ x, const float* __restrict__ w,
                  const int* __restrict__ target,
                  float* __restrict__ sumexp, float* __restrict__ sumlog,
                  float* __restrict__ tgtlogit)
{
    constexpr int BK = 32;
    constexpr int LDA = 40;
    __shared__ __bf16 As[BM * LDA];
    __shared__ __bf16 Bs[BN * LDA];
    __shared__ int tgt_s[BM];

    const int tid  = threadIdx.x;
    const int lane = tid & 63;
    const int wid  = tid >> 6;
    const int wm   = wid & 1;
    const int wn   = wid >> 1;
    const int bid  = blockIdx.x;
    const int m0   = (bid & (MT - 1)) * BM;
    const int n0   = (bid / MT) * BN;

    if (tid < BM) tgt_s[tid] = target[m0 + tid];

    floatx4 acc[4][4] = {};
    const int qr = lane >> 4;
    const int cr = lane & 15;

    for (int k0 = 0; k0 < Kdim; k0 += BK) {
        __syncthreads();
        #pragma unroll
        for (int i = 0; i < 4; ++i) {
            int idx = tid + i * 256;
            int row = idx >> 3;
            int c4  = (idx & 7) * 4;
            float4 v = *(const float4*)(x + (size_t)(m0 + row) * Kdim + k0 + c4);
            bf16x4 p;
            p[0] = (__bf16)v.x; p[1] = (__bf16)v.y; p[2] = (__bf16)v.z; p[3] = (__bf16)v.w;
            *(bf16x4*)&As[row * LDA + c4] = p;
        }
        #pragma unroll
        for (int i = 0; i < 4; ++i) {
            int idx = tid + i * 256;
            int row = idx >> 3;
            int c4  = (idx & 7) * 4;
            float4 v = *(const float4*)(w + (size_t)(n0 + row) * Kdim + k0 + c4);
            bf16x4 p;
            p[0] = (__bf16)v.x; p[1] = (__bf16)v.y; p[2] = (__bf16)v.z; p[3] = (__bf16)v.w;
            *(bf16x4*)&Bs[row * LDA + c4] = p;
        }
        __syncthreads();

        bf16x8 afrag[4], bfrag[4];
        #pragma unroll
        for (int mi = 0; mi < 4; ++mi)
            afrag[mi] = *(const bf16x8*)&As[(wm * 64 + mi * 16 + cr) * LDA + qr * 8];
        #pragma unroll
        for (int ni = 0; ni < 4; ++ni)
            bfrag[ni] = *(const bf16x8*)&Bs[(wn * 64 + ni * 16 + cr) * LDA + qr * 8];

        #pragma unroll
        for (int mi = 0; mi < 4; ++mi)
            #pragma unroll
            for (int ni = 0; ni < 4; ++ni)
                acc[mi][ni] = __builtin_amdgcn_mfma_f32_16x16x32_bf16(
                    afrag[mi], bfrag[ni], acc[mi][ni], 0, 0, 0);
    }

    #pragma unroll
    for (int mi = 0; mi < 4; ++mi) {
        #pragma unroll
        for (int reg = 0; reg < 4; ++reg) {
            const int lrow = wm * 64 + mi * 16 + qr * 4 + reg;
            const int grow = m0 + lrow;
            const int t = tgt_s[lrow];
            float se = 0.f, sl = 0.f;
            #pragma unroll
            for (int ni = 0; ni < 4; ++ni) {
                float v = acc[mi][ni][reg];
                int gcol = n0 + wn * 64 + ni * 16 + cr;
                if (t == gcol) tgtlogit[grow] = v;
                se += __expf(v);
                sl += v;
            }
            #pragma unroll
            for (int st = 1; st < 16; st <<= 1) {
                se += __shfl_xor(se, st, 64);
                sl += __shfl_xor(sl, st, 64);
            }
            if (cr == 0) {
                atomicAdd(&sumexp[grow], se);
                atomicAdd(&sumlog[grow], sl);
            }
        }
    }
}

// One block, 8 waves: wave w reduces sequence w (512 tokens).
__global__ void dpo_finalize(const float* __restrict__ sumexp,
                             const float* __restrict__ sumlog,
                             const float* __restrict__ tgtlogit,
                             const int* __restrict__ target,
                             float* __restrict__ out)
{
    __shared__ float s_logp[8], s_sl[8];
    const int lane = threadIdx.x & 63;
    const int w    = threadIdx.x >> 6;

    float lp = 0.f, cnt = 0.f, sl = 0.f;
    #pragma unroll
    for (int i = 0; i < 8; ++i) {
        int t  = w * 512 + i * 64 + lane;
        int tg = target[t];
        if (tg != IGNORE_INDEX) {
            lp  += tgtlogit[t] - logf(sumexp[t]);
            cnt += 1.f;
        }
        sl += sumlog[t];
    }
    #pragma unroll
    for (int s = 1; s < 64; s <<= 1) {
        lp  += __shfl_xor(lp, s, 64);
        cnt += __shfl_xor(cnt, s, 64);
        sl  += __shfl_xor(sl, s, 64);
    }
    if (lane == 0) { s_logp[w] = lp / cnt; s_sl[w] = sl; }
    __syncthreads();

    if (threadIdx.x == 0) {
        float cm = 0.f, rm = 0.f, loss = 0.f;
        for (int i = 0; i < 4; ++i) { cm += s_sl[i]; rm += s_sl[4 + i]; }
        const float denom = 4.f * 512.f * 32000.f;
        cm /= denom; rm /= denom;
        for (int i = 0; i < 4; ++i) {
            float d = BETA * (s_logp[i] - s_logp[4 + i]);
            float l = (d > 0.f) ? log1pf(expf(-d)) : (-d + log1pf(expf(d)));
            loss += l;
        }
        loss *= 0.25f;
        out[0] = loss;
        for (int i = 0; i < 4; ++i) out[1 + i] = s_logp[i];
        for (int i = 0; i < 4; ++i) out[5 + i] = s_logp[4 + i];
        out[9]  = cm;
        out[10] = rm;
        out[11] = 0.f;
    }
}

extern "C" void kernel_launch(void* const* d_in, const int* in_sizes, int n_in,
                              void* d_out, int out_size, void* d_ws, size_t ws_size,
                              hipStream_t stream) {
    const float* x      = (const float*)d_in[0];   // (8,512,4096) fp32
    const float* wgt    = (const float*)d_in[1];   // (32000,4096) fp32
    const int*   target = (const int*)d_in[2];     // (8,512) int32
    float* out = (float*)d_out;

    // ws layout: [sumexp 4096][sumlog 4096][tgtlogit 4096] floats, then fp8 x, then fp8 w
    float* sumexp   = (float*)d_ws;
    float* sumlog   = sumexp + Mdim;
    float* tgtlogit = sumlog + Mdim;
    char*  base     = (char*)d_ws + 3 * Mdim * sizeof(float);            // 49152 B
    unsigned char* x8 = (unsigned char*)base;                            // 16,777,216 B
    unsigned char* w8 = x8 + (size_t)Mdim * Kdim;                        // 131,072,000 B

    const size_t ws_needed = 3 * Mdim * sizeof(float)
                           + (size_t)Mdim * Kdim
                           + (size_t)Ndim * Kdim;

    hipMemsetAsync(d_ws, 0, 2 * Mdim * sizeof(float), stream);   // zero atomic accumulators

    if (ws_size >= ws_needed) {
        const long nx = (long)Mdim * Kdim;       // 16,777,216
        const long nw = (long)Ndim * Kdim;       // 131,072,000
        cvt_f32_fp8<<<(int)(nx / 16 / 256), 256, 0, stream>>>(x,   (uint*)x8, nx);
        cvt_f32_fp8<<<(int)(nw / 16 / 256), 256, 0, stream>>>(wgt, (uint*)w8, nw);
        dpo_gemm_fp8<<<MT * NT, 256, 0, stream>>>(x8, w8, target, sumexp, sumlog, tgtlogit);
    } else {
        dpo_gemm_f32<<<MT * NT, 256, 0, stream>>>(x, wgt, target, sumexp, sumlog, tgtlogit);
    }
    dpo_finalize<<<1, 512, 0, stream>>>(sumexp, sumlog, tgtlogit, target, out);
}